// Round 13
// baseline (38.244 us; speedup 1.0000x reference)
//
#include <hip/hip_runtime.h>
#include <math.h>

#define HD 256
#define SD 768
#define D2 512
#define NE 8
#define NB 32
#define NBLK 256
#define NTHR 256
#define SFP 516   // padded row stride for [32][512] staging

typedef float f32x4 __attribute__((ext_vector_type(4)));
typedef unsigned u32x4 __attribute__((ext_vector_type(4)));

__device__ __forceinline__ float gelu_exact(float x) {
    return 0.5f * x * (1.0f + erff(x * 0.70710678118654752f));
}

// ---- Coherent (L2-bypassing) access for cross-block intermediates ----------
__device__ __forceinline__ void cstf(float* p, float v) {
    __hip_atomic_store(p, v, __ATOMIC_RELAXED, __HIP_MEMORY_SCOPE_AGENT);
}
__device__ __forceinline__ float cldf(const float* p) {
    return __hip_atomic_load(p, __ATOMIC_RELAXED, __HIP_MEMORY_SCOPE_AGENT);
}
__device__ __forceinline__ void csti(int* p, int v) {
    __hip_atomic_store(p, v, __ATOMIC_RELAXED, __HIP_MEMORY_SCOPE_AGENT);
}
__device__ __forceinline__ int cldi(const int* p) {
    return __hip_atomic_load(p, __ATOMIC_RELAXED, __HIP_MEMORY_SCOPE_AGENT);
}

// Bulk-stage 64KB global->LDS ([32][SFP]), 16 pipelined coherent dwordx4
// loads, one vmcnt drain, LDS float4 writes (R6, verified).
__device__ __forceinline__ void stage16k(const float* __restrict__ gsrc,
                                         float* __restrict__ lds, int t)
{
    const f32x4* src = (const f32x4*)gsrc;
    f32x4 r[16];
    #pragma unroll
    for (int j = 0; j < 16; ++j) {
        const f32x4* p = src + (t + j * 256);
        asm volatile("global_load_dwordx4 %0, %1, off sc0 sc1"
                     : "=v"(r[j]) : "v"(p));
    }
    asm volatile("s_waitcnt vmcnt(0)" ::: "memory");
    __builtin_amdgcn_sched_barrier(0);
    #pragma unroll
    for (int j = 0; j < 16; ++j) {
        int q = t + j * 256;
        *(f32x4*)&lds[(q >> 7) * SFP + (q & 127) * 4] = r[j];
    }
}

// ---- Sync primitives (R12, verified) ---------------------------------------
__device__ __forceinline__ void post_slot(unsigned* slots, unsigned tok) {
    __syncthreads();
    if (threadIdx.x == 0)
        __hip_atomic_store(slots + blockIdx.x, tok, __ATOMIC_RELAXED,
                           __HIP_MEMORY_SCOPE_AGENT);
}

__device__ __forceinline__ void finish_full(const unsigned* slots,
                                            unsigned* gen, unsigned tok) {
    const int t = threadIdx.x;
    if (blockIdx.x == 0) {
        if (t < 64) {
            const u32x4* p = (const u32x4*)slots + t;
            for (;;) {
                u32x4 v;
                asm volatile("global_load_dwordx4 %0, %1, off sc0 sc1\n\t"
                             "s_waitcnt vmcnt(0)"
                             : "=&v"(v) : "v"(p) : "memory");
                bool ok = (v[0] == tok) & (v[1] == tok) &
                          (v[2] == tok) & (v[3] == tok);
                if (__ballot(ok) == ~0ull) break;
                __builtin_amdgcn_s_sleep(1);
            }
            if (t == 0)
                __hip_atomic_store(gen, tok, __ATOMIC_RELAXED,
                                   __HIP_MEMORY_SCOPE_AGENT);
        }
    } else {
        if (t == 0) {
            while (__hip_atomic_load(gen, __ATOMIC_RELAXED,
                                     __HIP_MEMORY_SCOPE_AGENT) != tok)
                __builtin_amdgcn_s_sleep(1);
        }
    }
    __builtin_amdgcn_fence(__ATOMIC_ACQUIRE, "workgroup");
    __syncthreads();
}

__device__ __forceinline__ void wait_subset(const unsigned* slots, int nq,
                                            unsigned tok) {
    if ((int)threadIdx.x < nq) {
        const u32x4* p = (const u32x4*)slots + threadIdx.x;
        for (;;) {
            u32x4 v;
            asm volatile("global_load_dwordx4 %0, %1, off sc0 sc1\n\t"
                         "s_waitcnt vmcnt(0)"
                         : "=&v"(v) : "v"(p) : "memory");
            if ((v[0] == tok) & (v[1] == tok) & (v[2] == tok) & (v[3] == tok))
                break;
            __builtin_amdgcn_s_sleep(2);
        }
    }
    __builtin_amdgcn_fence(__ATOMIC_ACQUIRE, "workgroup");
    __syncthreads();
}

__device__ __forceinline__ void wait_two_experts(const unsigned* slots,
                                                 int ea, int eb, unsigned tok) {
    if (threadIdx.x < 8) {
        int es = (threadIdx.x < 4) ? ea : eb;
        const u32x4* p = (const u32x4*)slots + es * 4 + (threadIdx.x & 3);
        for (;;) {
            u32x4 v;
            asm volatile("global_load_dwordx4 %0, %1, off sc0 sc1\n\t"
                         "s_waitcnt vmcnt(0)"
                         : "=&v"(v) : "v"(p) : "memory");
            if ((v[0] == tok) & (v[1] == tok) & (v[2] == tok) & (v[3] == tok))
                break;
            __builtin_amdgcn_s_sleep(2);
        }
    }
    __builtin_amdgcn_fence(__ATOMIC_ACQUIRE, "workgroup");
    __syncthreads();
}

// Shared-memory carve-up (floats)
#define S_F     0                    // 32*516 = 16512
#define S_W     16512                // 512*16 = 8192
#define S_R2    (16512 + 8192)       // 8*512 = 4096
#define S_RED   (16512 + 8192 + 4096)        // 256
#define S_SMALL (16512 + 8192 + 4096 + 256)  // 32
#define SMEM_F  (16512 + 8192 + 4096 + 256 + 32)

__global__ __launch_bounds__(256) void fused_all(
    const float* __restrict__ smiles,
    const float* __restrict__ sW, const float* __restrict__ sb,
    const float* __restrict__ Wv, const float* __restrict__ bv,
    const float* __restrict__ Wo, const float* __restrict__ bo,
    const float* __restrict__ gW, const float* __restrict__ gb,
    const float* __restrict__ W1, const float* __restrict__ b1,
    const float* __restrict__ W2, const float* __restrict__ b2,
    const float* __restrict__ lng, const float* __restrict__ lnb,
    const float* __restrict__ clsW, const float* __restrict__ clsb,
    float* __restrict__ proj, float* __restrict__ fused,
    float* __restrict__ probs, float* __restrict__ pn,
    int* __restrict__ sel, float* __restrict__ h1,
    float* __restrict__ eo, float* __restrict__ Mws,
    float* __restrict__ attb,
    unsigned* __restrict__ slot0, unsigned* __restrict__ slot1,
    unsigned* __restrict__ slot2, unsigned* __restrict__ slot3,
    unsigned* __restrict__ gen, unsigned* __restrict__ LC,
    float* __restrict__ out)
{
    __shared__ __align__(16) float smem[SMEM_F];
    __shared__ unsigned s_lc;
    const int bid = blockIdx.x, t = threadIdx.x;

    if (t == 0)
        s_lc = __hip_atomic_load(LC, __ATOMIC_RELAXED, __HIP_MEMORY_SCOPE_AGENT);
    __syncthreads();
    const unsigned tb = s_lc * 2654435761u;

    // ---------------- P0: proj = smiles @ sW + sb (256 blocks) ----------------
    {
        int r = bid >> 3, sl = bid & 7;
        float* s_in = smem + S_F;                   // 768
        float* s_red = smem + S_RED;
        const float* srow = smiles + (size_t)r * SD;
        for (int i = t; i < SD / 4; i += NTHR)
            ((float4*)s_in)[i] = ((const float4*)srow)[i];
        __syncthreads();
        int c = t & 31, kq = t >> 5;                // 32 cols x 8 k-quadrants
        float acc = 0.f;
        const float* wp = sW + (size_t)(kq * 96) * HD + sl * 32 + c;
        #pragma unroll 8
        for (int k = 0; k < 96; ++k)
            acc = fmaf(s_in[kq * 96 + k], wp[(size_t)k * HD], acc);
        s_red[t] = acc;
        __syncthreads();
        if (t < 32) {
            float s = 0.f;
            #pragma unroll
            for (int q = 0; q < 8; ++q) s += s_red[q * 32 + t];
            int col = sl * 32 + t;
            s += sb[col];
            cstf(proj + r * HD + col, s);
            cstf(fused + (size_t)r * 2 * HD + HD + col, s);   // 2nd half = proj
        }
    }

    // ---- Phase-0 extra: M = Wv@Wo tile (16x16 per block, 256 tiles = full
    // 256x256), bias row attb = bv@Wo + bo by tile-row-0 blocks. No input
    // deps -> runs before slot0 post; P1 then needs ONE GEMV instead of two.
    {
        int ti = bid >> 4, tj = bid & 15;
        int k0 = ti * 16, c0 = tj * 16;
        float* sA = smem + S_F;              // [16][260] Wv rows k0..k0+15
        float* sB = smem + S_F + 4160;       // [256][16] Wo cols c0..c0+15
        float* s_red = smem + S_RED;
        __syncthreads();   // P0's s_red reads done; s_in region reusable
        #pragma unroll
        for (int j = 0; j < 4; ++j) {
            int q = t + j * 256;             // 0..1023
            int r = q >> 6, kq4 = q & 63;
            *(f32x4*)&sA[r * 260 + kq4 * 4] =
                *(const f32x4*)(Wv + (size_t)(k0 + r) * HD + kq4 * 4);
        }
        #pragma unroll
        for (int j = 0; j < 4; ++j) {
            int q = t + j * 256;
            int kk = q >> 2, c4 = q & 3;
            *(f32x4*)&sB[kk * 16 + c4 * 4] =
                *(const f32x4*)(Wo + (size_t)kk * HD + c0 + c4 * 4);
        }
        __syncthreads();
        int r = t >> 4, c = t & 15;
        float acc = 0.f;
        #pragma unroll 8
        for (int kk = 0; kk < 256; ++kk)
            acc = fmaf(sA[r * 260 + kk], sB[kk * 16 + c], acc);
        cstf(Mws + (size_t)(k0 + r) * HD + c0 + c, acc);
        if (ti == 0) {       // block-uniform branch: internal barriers safe
            int ks2 = t >> 4, c2 = t & 15;
            float pacc = 0.f;
            #pragma unroll
            for (int kk = 0; kk < 16; ++kk)
                pacc = fmaf(bv[ks2 * 16 + kk], sB[(ks2 * 16 + kk) * 16 + c2], pacc);
            s_red[t] = pacc;
            __syncthreads();
            if (t < 16) {
                float s = 0.f;
                #pragma unroll
                for (int q2 = 0; q2 < 16; ++q2) s += s_red[q2 * 16 + t];
                cstf(attb + c0 + t, s + bo[c0 + t]);
            }
        }
    }
    post_slot(slot0, tb + 1u);

    // ---------------- P1: att = proj@M + attb -> gate/top2 (32 blocks) --------
    if (bid < NB) {
        wait_subset(slot0, 64, tb + 1u);   // ALL phase-0 producers (proj+M+attb)
        int b = bid;
        float* s_p   = smem + S_F;           // 256
        float* s_f2  = smem + S_F + 512;     // 512
        float* s_acc = smem + S_R2;          // 1024
        float* s_red = smem + S_RED;
        float* s_gate = smem + S_SMALL;
        s_p[t] = cldf(proj + b * HD + t);
        __syncthreads();
        int ks = t >> 6, cg = t & 63;        // 4 k-splits x 64 col-quads

        f32x4 acc4 = {0.f, 0.f, 0.f, 0.f};
        #pragma unroll
        for (int rr = 0; rr < 4; ++rr) {     // 16-deep pipelined sc1 reads of M
            f32x4 m[16];
            #pragma unroll
            for (int j = 0; j < 16; ++j) {
                const f32x4* p = (const f32x4*)
                    (Mws + (size_t)(ks * 64 + rr * 16 + j) * HD + cg * 4);
                asm volatile("global_load_dwordx4 %0, %1, off sc0 sc1"
                             : "=v"(m[j]) : "v"(p));
            }
            asm volatile("s_waitcnt vmcnt(0)" ::: "memory");
            __builtin_amdgcn_sched_barrier(0);
            #pragma unroll
            for (int j = 0; j < 16; ++j)
                acc4 += s_p[ks * 64 + rr * 16 + j] * m[j];
        }
        *(f32x4*)&s_acc[ks * 256 + cg * 4] = acc4;
        __syncthreads();
        float att = s_acc[t] + s_acc[256 + t] + s_acc[512 + t] + s_acc[768 + t]
                  + cldf(attb + t);
        s_f2[t] = att;
        s_f2[HD + t] = s_p[t];
        cstf(fused + (size_t)b * 2 * HD + t, att);
        __syncthreads();

        int e = t & 7, ch = t >> 3;
        float gp = 0.f;
        #pragma unroll
        for (int j = 0; j < 16; ++j) {
            int d = ch * 16 + j;
            gp = fmaf(s_f2[d], gW[d * NE + e], gp);
        }
        s_red[t] = gp;
        __syncthreads();
        for (int off = 128; off >= 8; off >>= 1) {
            if (t < off) s_red[t] += s_red[t + off];
            __syncthreads();
        }
        if (t < NE) s_gate[t] = s_red[t] + gb[t];
        __syncthreads();
        if (t == 0) {
            float m = s_gate[0];
            for (int i = 1; i < NE; ++i) m = fmaxf(m, s_gate[i]);
            float ex[NE], ssum = 0.f;
            for (int i = 0; i < NE; ++i) { ex[i] = expf(s_gate[i] - m); ssum += ex[i]; }
            float pr[NE];
            for (int i = 0; i < NE; ++i) { pr[i] = ex[i] / ssum; cstf(probs + b * NE + i, pr[i]); }
            int i1 = 0;
            for (int i = 1; i < NE; ++i) if (pr[i] > pr[i1]) i1 = i;
            int i2 = (i1 == 0) ? 1 : 0;
            for (int i = 0; i < NE; ++i) if (i != i1 && pr[i] > pr[i2]) i2 = i;
            float p1 = pr[i1], p2 = pr[i2], s12 = p1 + p2;
            csti(sel + b * 2 + 0, i1);
            csti(sel + b * 2 + 1, i2);
            cstf(pn + b * 2 + 0, p1 / s12);
            cstf(pn + b * 2 + 1, p2 / s12);
        }
    }
    post_slot(slot1, tb + 2u);

    // prefetch this block's W1 tile into LDS during the barrier window
    {
        int e = bid >> 5, ct = bid & 31;
        float* s_w = smem + S_W;
        const float* Wb = W1 + (size_t)e * D2 * D2 + ct * 16;
        #pragma unroll
        for (int j = 0; j < 8; ++j) {
            int q = t + j * 256;
            int k = q >> 2, c4 = (q & 3) * 4;
            *(float4*)&s_w[k * 16 + c4] = *(const float4*)(Wb + (size_t)k * D2 + c4);
        }
    }
    finish_full(slot1, gen + 0, tb + 2u);   // P1 -> P2: 256 waiters, hierarchical

    // ------- P2: h1 = gelu(fused @ W1[e] + b1[e]) (ks=8, 4r x 4c tile) --------
    {
        int e = bid >> 5, ct = bid & 31;
        float* s_f  = smem + S_F;
        float* s_w  = smem + S_W;
        float* s_r2 = smem + S_R2;   // [8 ks][512 outs]
        stage16k(fused, s_f, t);
        __syncthreads();
        int ks = t >> 5, l = t & 31;
        int rg = l >> 2, c4g = l & 3;
        const float* wb = s_w + c4g * 4;
        int k0 = ks * 64;
        f32x4 a0 = {0.f,0.f,0.f,0.f}, a1 = a0, a2 = a0, a3 = a0;
        #pragma unroll 2
        for (int kq = 0; kq < 16; ++kq) {
            int k = k0 + kq * 4;
            f32x4 w0 = *(const f32x4*)&wb[(k + 0) * 16];
            f32x4 w1 = *(const f32x4*)&wb[(k + 1) * 16];
            f32x4 w2 = *(const f32x4*)&wb[(k + 2) * 16];
            f32x4 w3 = *(const f32x4*)&wb[(k + 3) * 16];
            f32x4 f0 = *(const f32x4*)&s_f[(rg     ) * SFP + k];
            f32x4 f1 = *(const f32x4*)&s_f[(rg +  8) * SFP + k];
            f32x4 f2 = *(const f32x4*)&s_f[(rg + 16) * SFP + k];
            f32x4 f3 = *(const f32x4*)&s_f[(rg + 24) * SFP + k];
            a0 += f0[0]*w0 + f0[1]*w1 + f0[2]*w2 + f0[3]*w3;
            a1 += f1[0]*w0 + f1[1]*w1 + f1[2]*w2 + f1[3]*w3;
            a2 += f2[0]*w0 + f2[1]*w1 + f2[2]*w2 + f2[3]*w3;
            a3 += f3[0]*w0 + f3[1]*w1 + f3[2]*w2 + f3[3]*w3;
        }
        *(f32x4*)&s_r2[ks * 512 + (rg     ) * 16 + c4g * 4] = a0;
        *(f32x4*)&s_r2[ks * 512 + (rg +  8) * 16 + c4g * 4] = a1;
        *(f32x4*)&s_r2[ks * 512 + (rg + 16) * 16 + c4g * 4] = a2;
        *(f32x4*)&s_r2[ks * 512 + (rg + 24) * 16 + c4g * 4] = a3;
        __syncthreads();
        #pragma unroll
        for (int o = 0; o < 2; ++o) {
            int outi = t * 2 + o;
            float s = 0.f;
            #pragma unroll
            for (int p = 0; p < 8; ++p) s += s_r2[p * 512 + outi];
            int r = outi >> 4, cl = outi & 15;
            int col = ct * 16 + cl;
            cstf(h1 + ((size_t)e * NB + r) * D2 + col,
                 gelu_exact(s + b1[e * D2 + col]));
        }
    }
    post_slot(slot2, tb + 3u);
    if (bid >= 128) return;          // done — frees CUs for P3

    // prefetch this block's W2 tile during the wait window
    {
        int e = bid >> 4, ct = bid & 15;
        float* s_w = smem + S_W;
        const float* Wb = W2 + (size_t)e * D2 * HD + ct * 16;
        #pragma unroll
        for (int j = 0; j < 8; ++j) {
            int q = t + j * 256;
            int k = q >> 2, c4 = (q & 3) * 4;
            *(float4*)&s_w[k * 16 + c4] = *(const float4*)(Wb + (size_t)k * HD + c4);
        }
    }
    // P2 -> P3: direct expert-subset wait (R12, verified)
    {
        int e = bid >> 4;
        wait_subset(slot2 + e * 32, 8, tb + 3u);
    }

    // ------- P3: eo = h1 @ W2[e] + b2[e] (ks=8, 4r x 4c tile) -----------------
    {
        int e = bid >> 4, ct = bid & 15;
        float* s_f  = smem + S_F;
        float* s_w  = smem + S_W;
        float* s_r2 = smem + S_R2;
        stage16k(h1 + (size_t)e * NB * D2, s_f, t);
        __syncthreads();
        int ks = t >> 5, l = t & 31;
        int rg = l >> 2, c4g = l & 3;
        const float* wb = s_w + c4g * 4;
        int k0 = ks * 64;
        f32x4 a0 = {0.f,0.f,0.f,0.f}, a1 = a0, a2 = a0, a3 = a0;
        #pragma unroll 2
        for (int kq = 0; kq < 16; ++kq) {
            int k = k0 + kq * 4;
            f32x4 w0 = *(const f32x4*)&wb[(k + 0) * 16];
            f32x4 w1 = *(const f32x4*)&wb[(k + 1) * 16];
            f32x4 w2 = *(const f32x4*)&wb[(k + 2) * 16];
            f32x4 w3 = *(const f32x4*)&wb[(k + 3) * 16];
            f32x4 f0 = *(const f32x4*)&s_f[(rg     ) * SFP + k];
            f32x4 f1 = *(const f32x4*)&s_f[(rg +  8) * SFP + k];
            f32x4 f2 = *(const f32x4*)&s_f[(rg + 16) * SFP + k];
            f32x4 f3 = *(const f32x4*)&s_f[(rg + 24) * SFP + k];
            a0 += f0[0]*w0 + f0[1]*w1 + f0[2]*w2 + f0[3]*w3;
            a1 += f1[0]*w0 + f1[1]*w1 + f1[2]*w2 + f1[3]*w3;
            a2 += f2[0]*w0 + f2[1]*w1 + f2[2]*w2 + f2[3]*w3;
            a3 += f3[0]*w0 + f3[1]*w1 + f3[2]*w2 + f3[3]*w3;
        }
        *(f32x4*)&s_r2[ks * 512 + (rg     ) * 16 + c4g * 4] = a0;
        *(f32x4*)&s_r2[ks * 512 + (rg +  8) * 16 + c4g * 4] = a1;
        *(f32x4*)&s_r2[ks * 512 + (rg + 16) * 16 + c4g * 4] = a2;
        *(f32x4*)&s_r2[ks * 512 + (rg + 24) * 16 + c4g * 4] = a3;
        __syncthreads();
        #pragma unroll
        for (int o = 0; o < 2; ++o) {
            int outi = t * 2 + o;
            float s = 0.f;
            #pragma unroll
            for (int p = 0; p < 8; ++p) s += s_r2[p * 512 + outi];
            int r = outi >> 4, cl = outi & 15;
            int col = ct * 16 + cl;
            cstf(eo + ((size_t)e * NB + r) * HD + col, s + b2[e * HD + col]);
        }
    }
    post_slot(slot3, tb + 4u);
    if (bid >= NB) return;           // only 32 blocks do P4

    // ---------------- P4: gather/combine, LN, classifier, aux (32 blocks) -----
    {
        int b = bid;
        float* s_red = smem + S_RED;
        float* s_stats = smem + S_SMALL;   // 32 slots
        int e0 = cldi(sel + b * 2 + 0), e1 = cldi(sel + b * 2 + 1);
        float p0 = cldf(pn + b * 2 + 0), p1 = cldf(pn + b * 2 + 1);

        wait_two_experts(slot3, e0, e1, tb + 4u);

        float moe = p0 * cldf(eo + ((size_t)e0 * NB + b) * HD + t)
                  + p1 * cldf(eo + ((size_t)e1 * NB + b) * HD + t);
        int wv = t >> 6, ln = t & 63;

        // mean (wave shuffle + 4-slot combine)
        float ssum = moe;
        #pragma unroll
        for (int off = 32; off > 0; off >>= 1) ssum += __shfl_down(ssum, off, 64);
        if (ln == 0) s_stats[4 + wv] = ssum;
        __syncthreads();
        float mu = (s_stats[4] + s_stats[5] + s_stats[6] + s_stats[7]) * (1.f / HD);
        float d = moe - mu;

        // variance
        float vs = d * d;
        #pragma unroll
        for (int off = 32; off > 0; off >>= 1) vs += __shfl_down(vs, off, 64);
        if (ln == 0) s_stats[8 + wv] = vs;
        __syncthreads();
        float var = (s_stats[8] + s_stats[9] + s_stats[10] + s_stats[11]) * (1.f / HD);

        float y = fmaf(d * rsqrtf(var + 1e-5f), lng[t], lnb[t]);

        // classifier cols 0 and 1, fused reduce
        float c0 = y * clsW[t * 2 + 0], c1 = y * clsW[t * 2 + 1];
        #pragma unroll
        for (int off = 32; off > 0; off >>= 1) {
            c0 += __shfl_down(c0, off, 64);
            c1 += __shfl_down(c1, off, 64);
        }
        if (ln == 0) { s_stats[12 + wv] = c0; s_stats[16 + wv] = c1; }
        __syncthreads();
        if (t == 0) {
            out[b * 2 + 0] = s_stats[12] + s_stats[13] + s_stats[14] + s_stats[15]
                           + clsb[0];
            out[b * 2 + 1] = s_stats[16] + s_stats[17] + s_stats[18] + s_stats[19]
                           + clsb[1];
        }

        if (bid == 0) {
            __syncthreads();
            s_red[t] = cldf(probs + t);
            __syncthreads();
            for (int off = 128; off >= 8; off >>= 1) {
                if (t < off) s_red[t] += s_red[t + off];
                __syncthreads();
            }
            if (t == 0) {
                float aux = 0.f;
                for (int e = 0; e < NE; ++e) {
                    float u = s_red[e] * (1.f / 32.f);
                    aux += u * logf(0.125f) - logf(u) * 0.125f;
                }
                out[64] = 0.1f * aux;
            }
        }
    }

    // LC bump: block 0 first verifies all 256 blocks posted slot2 (they all
    // long since read LC) — instant poll round — then bumps.
    if (bid == 0) {
        wait_subset(slot2, 64, tb + 3u);
        if (t == 0)
            __hip_atomic_store(LC, s_lc + 1u, __ATOMIC_RELAXED,
                               __HIP_MEMORY_SCOPE_AGENT);
    }
}

extern "C" void kernel_launch(void* const* d_in, const int* in_sizes, int n_in,
                              void* d_out, int out_size, void* d_ws, size_t ws_size,
                              hipStream_t stream) {
    (void)in_sizes; (void)n_in; (void)out_size; (void)ws_size;
    const float* smiles = (const float*)d_in[2];
    const float* sW  = (const float*)d_in[7];
    const float* sb  = (const float*)d_in[8];
    const float* Wv  = (const float*)d_in[13];
    const float* bv  = (const float*)d_in[14];
    const float* Wo  = (const float*)d_in[15];
    const float* bo  = (const float*)d_in[16];
    const float* gW  = (const float*)d_in[17];
    const float* gb  = (const float*)d_in[18];
    const float* W1  = (const float*)d_in[19];
    const float* b1  = (const float*)d_in[20];
    const float* W2  = (const float*)d_in[21];
    const float* b2  = (const float*)d_in[22];
    const float* lng = (const float*)d_in[23];
    const float* lnb = (const float*)d_in[24];
    const float* cW  = (const float*)d_in[25];
    const float* cb  = (const float*)d_in[26];
    float* out = (float*)d_out;
    float* ws  = (float*)d_ws;

    float*    proj  = ws;                      // 8192
    float*    fused = ws + 8192;               // 16384
    float*    probs = ws + 24576;              // 256
    float*    pn    = ws + 24832;              // 64
    int*      sel   = (int*)(ws + 24896);      // 64
    float*    h1    = ws + 24960;              // 131072
    float*    eo    = ws + 156032;             // 65536; Mws aliases (disjoint in time)
    float*    Mws   = eo;                      // 256x256, written P0, read P1
    unsigned* slot0 = (unsigned*)(ws + 221568);// 256
    unsigned* slot1 = (unsigned*)(ws + 221824);// 256
    unsigned* slot2 = (unsigned*)(ws + 222080);// 256
    unsigned* slot3 = (unsigned*)(ws + 222336);// 128 (16 per expert)
    unsigned* gen   = (unsigned*)(ws + 222592);// 4
    unsigned* LC    = (unsigned*)(ws + 222596);// 1
    float*    attb  = ws + 222608;             // 256 (att bias row, 16-aligned)

    fused_all<<<NBLK, NTHR, 0, stream>>>(
        smiles, sW, sb, Wv, bv, Wo, bo, gW, gb, W1, b1, W2, b2,
        lng, lnb, cW, cb,
        proj, fused, probs, pn, sel, h1, eo, Mws, attb,
        slot0, slot1, slot2, slot3, gen, LC, out);
}